// Round 14
// baseline (20013.519 us; speedup 1.0000x reference)
//
#include <hip/hip_runtime.h>
#include <hip/hip_fp16.h>
#include <cmath>

#define LNUM 6
#define DM   1152
#define DHEAD 256
#define NH   4
#define FF   6912
#define VOC  65536
#define HIST 4095
#define SEQ  4096
#define EPSV 1e-6f
#define NB   1024

// ---- ws float offsets ----
#define POP_O   0          // [128][1024]
#define SPS_O   131072     // [128][4]
#define QKVP_O  131584     // [18][1536]
#define APP_O   159232     // [16][1152]
#define DPP_O   177664     // [27][1152]
#define GUP_O   208768     // [18][13824]
#define HIN_O   457600     // [1152]
#define HM_O    458752     // [1152]
#define XN0_O   459904     // [1152]
#define AMX_O   461056     // u64 (8B aligned)
#define CNT_O   461058     // u32 (fallback uses [16] here too)
#define GCL_O   461059     // u32 barrier global
#define GC_O    461060     // u32[64] barrier groups
#define INIT_END 461124    // memset covers AMX..GC

struct P {
    const int* ids; const int* aflag;
    const float* kc; const float* vc;
    const int* tbl; const float* esc; const float* ezp;
    const float* w_in; const float* w_qn; const float* w_kn;
    const float* Wq; const float* Wk; const float* Wv; const float* Wo;
    const float* w_pa; const float* w_pf; const float* w_pof;
    const float* Wg; const float* Wu; const float* Wd;
    const float* w_fin; const float* Wlm;
    float* keys; float* vals; float* tok; float* ws;
};

__device__ __forceinline__ float bs256(float v, float* red4) {
#pragma unroll
    for (int off = 32; off; off >>= 1) v += __shfl_xor(v, off);
    int t = threadIdx.x;
    if ((t & 63) == 0) red4[t >> 6] = v;
    __syncthreads();
    float r = red4[0] + red4[1] + red4[2] + red4[3];
    __syncthreads();
    return r;
}

// two-level grid barrier: 64 groups x 16 blocks, monotonic epochs
__device__ __forceinline__ void gbar(unsigned* gcl, unsigned* gc, int* ep) {
    __syncthreads();
    if (threadIdx.x == 0) {
        __threadfence();
        unsigned g = blockIdx.x >> 4;
        unsigned e = (unsigned)(*ep);
        unsigned a = __hip_atomic_fetch_add(&gc[g], 1u, __ATOMIC_ACQ_REL,
                                            __HIP_MEMORY_SCOPE_AGENT) + 1u;
        if (a == 16u * e)
            __hip_atomic_fetch_add(gcl, 1u, __ATOMIC_ACQ_REL, __HIP_MEMORY_SCOPE_AGENT);
        while (__hip_atomic_load(gcl, __ATOMIC_ACQUIRE, __HIP_MEMORY_SCOPE_AGENT) < 64u * e)
            __builtin_amdgcn_s_sleep(8);
        __threadfence();
    }
    __syncthreads();
    ++(*ep);
}

// ==================== cooperative mega: 1024 blocks x 256 threads ====================
__global__ __launch_bounds__(256, 4) void mega(P p) {
    __shared__ __align__(16) float sm[3072];
    const int t = threadIdx.x, bid = blockIdx.x;
    float* ws = p.ws;
    unsigned* gcl = (unsigned*)(ws + GCL_O);
    unsigned* gc  = (unsigned*)(ws + GC_O);
    int ep = 1;

    // ---------- P0: cache copies + embed ----------
    for (int u = bid; u < 30721; u += NB) {
        if (u < 24576) {
            int row = u >> 4;
            int s = ((u & 15) << 8) + t;
            if (s < HIST) p.keys[(size_t)row * SEQ + s] = p.kc[(size_t)row * HIST + s];
        } else if (u < 30720) {
            int r = (u - 24576) * 4 + (t >> 6);
            int d4 = t & 63;
            if (r < LNUM * HIST) {
                int l = r / HIST, sI = r - l * HIST;
                ((float4*)(p.vals + ((size_t)l * SEQ + sI) * DHEAD))[d4] =
                    ((const float4*)(p.vc + (size_t)r * DHEAD))[d4];
            }
        } else {
            float* xv = sm; float* red4 = sm + 1280;
            int tok = p.ids[0];
            float sc = p.esc[tok], z = p.ezp[tok];
            const int* row = p.tbl + (size_t)tok * DM;
            for (int i = t; i < DM; i += 256) xv[i] = (float)row[i] * sc + z;
            for (int i = t; i < DM; i += 256) ws[HIN_O + i] = xv[i];
            float ss = 0.f;
            for (int i = t; i < DM; i += 256) { float v = xv[i]; ss += v * v; }
            ss = bs256(ss, red4);
            float inv = 1.f / sqrtf(ss / DM + EPSV);
            for (int i = t; i < DM; i += 256) ws[XN0_O + i] = p.w_in[i] * xv[i] * inv;
        }
    }
    gbar(gcl, gc, &ep);

    for (int l = 0; l < LNUM; ++l) {
        // ---------- qkv phase (108 units) ----------
        if (bid < 108) {
            float* xv = sm; float* red4 = sm + 1152;
            float4* qred = (float4*)(sm + 1156 + 12);  // 16B-aligned region below
            qred = (float4*)(sm + 1184);
            int bx = bid % 6, by = bid / 6;
            if (l > 0) {
                const float* dpp = ws + DPP_O;
                for (int i = t; i < DM; i += 256) {
                    float d = 0.f;
#pragma unroll
                    for (int p2 = 0; p2 < 27; ++p2) d += dpp[p2 * DM + i];
                    xv[i] = d;
                }
                float ss = 0.f;
                for (int i = t; i < DM; i += 256) { float d = xv[i]; ss += d * d; }
                ss = bs256(ss, red4);
                float inv = 1.f / sqrtf(ss / DM + EPSV);
                const float* wres = p.w_pof + (size_t)(l - 1) * DM;
                const float* hmp = ws + HM_O;
                for (int i = t; i < DM; i += 256) xv[i] = hmp[i] + wres[i] * xv[i] * inv;
                if (bid == 0)
                    for (int i = t; i < DM; i += 256) ws[HIN_O + i] = xv[i];
                float s2 = 0.f;
                for (int i = t; i < DM; i += 256) { float v = xv[i]; s2 += v * v; }
                s2 = bs256(s2, red4);
                float inv2 = 1.f / sqrtf(s2 / DM + EPSV);
                const float* wln = p.w_in + (size_t)l * DM;
                for (int i = t; i < DM; i += 256) xv[i] = wln[i] * xv[i] * inv2;
            } else {
                for (int i = t; i < DM; i += 256) xv[i] = ws[XN0_O + i];
            }
            __syncthreads();
            int f4c = t & 63, ks = t >> 6;
            int jf = bx * 64 + f4c;
            const float4* W4; int jj4, ncol4;
            if (jf < 256)      { W4 = (const float4*)(p.Wq + (size_t)l * DM * 1024); jj4 = jf;       ncol4 = 256; }
            else if (jf < 320) { W4 = (const float4*)(p.Wk + (size_t)l * DM * 256);  jj4 = jf - 256; ncol4 = 64; }
            else               { W4 = (const float4*)(p.Wv + (size_t)l * DM * 256);  jj4 = jf - 320; ncol4 = 64; }
            int i0 = by * 64 + ks * 16;
            float4 w[16];
#pragma unroll
            for (int r = 0; r < 16; ++r) w[r] = W4[(size_t)(i0 + r) * ncol4 + jj4];
            float4 acc = {0, 0, 0, 0};
#pragma unroll
            for (int r = 0; r < 16; ++r) {
                float xs = xv[i0 + r];
                acc.x += xs * w[r].x; acc.y += xs * w[r].y;
                acc.z += xs * w[r].z; acc.w += xs * w[r].w;
            }
            qred[t] = acc;
            __syncthreads();
            if (ks == 0) {
                float4 a = qred[f4c], b = qred[64 + f4c], c = qred[128 + f4c], d = qred[192 + f4c];
                float* dst = ws + QKVP_O + (size_t)by * 1536 + 4 * jf;
                dst[0] = a.x + b.x + c.x + d.x;
                dst[1] = a.y + b.y + c.y + d.y;
                dst[2] = a.z + b.z + c.z + d.z;
                dst[3] = a.w + b.w + c.w + d.w;
            }
        }
        gbar(gcl, gc, &ep);

        // ---------- attn phase (128 units) ----------
        if (bid < 128) {
            float* lq = sm;            // 1024
            float* lqf = sm + 1024;    // 1024
            float* lkn = sm + 2048;    // 256
            float* lkf = sm + 2304;    // 256
            float* lv  = sm + 2560;    // 256
            float* lp  = sm + 2816;    // 128
            float* red4 = sm + 2944;   // 4
            float* keys_l = p.keys + (size_t)l * DHEAD * SEQ;
            float* vals_l = p.vals + (size_t)l * SEQ * DHEAD;
            const float* qkvp = ws + QKVP_O;
            int s0 = bid * 32;
            bool last = (bid == 127);
            float base = ((l % 6) != 5) ? 1000000.f : 10000.f;
            int jm = t & 127;
            float theta = powf(base, -(float)(2 * jm) / 256.f);
            float ang = 4095.f * theta;
            float c = __half2float(__float2half(cosf(ang)));
            float s = __half2float(__float2half(sinf(ang)));
            for (int j = t; j < 1536; j += 256) {
                float v = 0.f;
#pragma unroll
                for (int p2 = 0; p2 < 18; ++p2) v += qkvp[p2 * 1536 + j];
                if (j < 1024) lq[j] = v;
                else if (j < 1280) lkn[j - 1024] = v;
                else lv[j - 1280] = v;
            }
            __syncthreads();
            const float* wqn = p.w_qn + (size_t)l * DHEAD;
            const float* wkn = p.w_kn + (size_t)l * DHEAD;
            int wv = t >> 6, ln = t & 63;
            float sq = 0.f, sk = 0.f;
#pragma unroll
            for (int j = 0; j < 4; ++j) {
                float v = lq[wv * 256 + j * 64 + ln]; sq += v * v;
                float u2 = lkn[j * 64 + ln];          sk += u2 * u2;
            }
#pragma unroll
            for (int off = 32; off; off >>= 1) { sq += __shfl_xor(sq, off); sk += __shfl_xor(sk, off); }
            float invq = 1.f / sqrtf(sq / 256.f + EPSV);
            float invk = 1.f / sqrtf(sk / 256.f + EPSV);
            __syncthreads();
#pragma unroll
            for (int j = 0; j < 4; ++j) {
                int d = j * 64 + ln;
                lq[wv * 256 + d] *= wqn[d] * invq;
                if (wv == 0) lkn[d] *= wkn[d] * invk;
            }
            __syncthreads();
            {
                float kn = lkn[t];
                float prk = (t < 128) ? -lkn[t + 128] : lkn[t - 128];
                lkf[t] = kn * c + prk * s;
#pragma unroll
                for (int h = 0; h < NH; ++h) {
                    float qn = lq[h * 256 + t];
                    float pr = (t < 128) ? -lq[h * 256 + t + 128] : lq[h * 256 + t - 128];
                    lqf[h * 256 + t] = qn * c + pr * s;
                }
            }
            __syncthreads();
            if (last) {
                keys_l[(size_t)t * SEQ + (SEQ - 1)] = lkf[t];
                vals_l[(size_t)(SEQ - 1) * DHEAD + t] = lv[t];
            }
            int sl = t & 31, dc = t >> 5;
            int sg = s0 + sl;
            bool self = last && (sl == 31);
            float a0 = 0, a1 = 0, a2 = 0, a3 = 0;
#pragma unroll 4
            for (int dd = 0; dd < 32; ++dd) {
                int d = dc * 32 + dd;
                float kv = self ? lkf[d] : keys_l[(size_t)d * SEQ + sg];
                a0 += lqf[d] * kv; a1 += lqf[256 + d] * kv;
                a2 += lqf[512 + d] * kv; a3 += lqf[768 + d] * kv;
            }
            __syncthreads();
            lq[t] = a0; lq[256 + t] = a1; lq[512 + t] = a2; lq[768 + t] = a3;
            __syncthreads();
            if (t < 32) {
                int af = p.aflag[0];
                float mk = (s0 + t > 0) ? -128.f * (float)af : 0.f;
                for (int h = 0; h < NH; ++h) {
                    float sc_ = 0.f;
#pragma unroll
                    for (int d8 = 0; d8 < 8; ++d8) sc_ += lq[h * 256 + d8 * 32 + t];
                    lp[h * 32 + t] = expf(sc_ + mk);
                }
            }
            __syncthreads();
            if (t < NH) {
                float su = 0.f;
                for (int i = 0; i < 32; ++i) su += lp[t * 32 + i];
                ws[SPS_O + bid * NH + t] = su;
            }
            float p0 = 0, p1 = 0, p2v = 0, p3 = 0;
#pragma unroll 4
            for (int ss_ = 0; ss_ < 32; ++ss_) {
                float v = (last && ss_ == 31) ? lv[t] : vals_l[(size_t)(s0 + ss_) * DHEAD + t];
                p0 += lp[ss_] * v;
                p1 += lp[32 + ss_] * v;
                p2v += lp[64 + ss_] * v;
                p3 += lp[96 + ss_] * v;
            }
            float* po = ws + POP_O + (size_t)bid * NH * DHEAD;
            po[t] = p0; po[256 + t] = p1; po[512 + t] = p2v; po[768 + t] = p3;
        }
        gbar(gcl, gc, &ep);

        // ---------- wo phase (80 units) ----------
        if (bid < 80) {
            float* x = sm;            // 64
            float* hinv = sm + 64;    // 4
            float* red4 = sm + 68;    // 4
            int bx = bid % 5, by = bid / 5;
            const float* sps = ws + SPS_O;
            const float* pop = ws + POP_O;
            for (int h = 0; h < NH; ++h) {
                float v = (t < 128) ? sps[t * NH + h] : 0.f;
                float tot = bs256(v, red4);
                if (t == 0) hinv[h] = 1.f / tot;
            }
            __syncthreads();
            int i0 = by * 64;
            if (t < 64) {
                float a = 0.f;
#pragma unroll 8
                for (int b = 0; b < 128; ++b) a += pop[(size_t)b * 1024 + i0 + t];
                x[t] = a * hinv[(i0 + t) >> 8];
            }
            __syncthreads();
            const float* Wo_l = p.Wo + (size_t)l * 1024 * DM;
            int j = bx * 256 + t;
            if (j < DM) {
                float acc = 0.f;
#pragma unroll 4
                for (int ii = 0; ii < 64; ++ii)
                    acc += x[ii] * Wo_l[(size_t)(i0 + ii) * DM + j];
                ws[APP_O + (size_t)by * DM + j] = acc;
            }
        }
        gbar(gcl, gc, &ep);

        // ---------- gu phase (972 units) ----------
        if (bid < 972) {
            float* xv = sm; float* red4 = sm + 1152;
            float4* gred = (float4*)(sm + 1184);
            const float* app = ws + APP_O;
            for (int i = t; i < DM; i += 256) {
                float a = 0.f;
#pragma unroll
                for (int p2 = 0; p2 < 16; ++p2) a += app[p2 * DM + i];
                xv[i] = a;
            }
            float ss = 0.f;
            for (int i = t; i < DM; i += 256) { float a = xv[i]; ss += a * a; }
            ss = bs256(ss, red4);
            float inv = 1.f / sqrtf(ss / DM + EPSV);
            const float* wpa = p.w_pa + (size_t)l * DM;
            const float* hin = ws + HIN_O;
            for (int i = t; i < DM; i += 256) xv[i] = hin[i] + wpa[i] * xv[i] * inv;
            if (bid == 0)
                for (int i = t; i < DM; i += 256) ws[HM_O + i] = xv[i];
            float s2 = 0.f;
            for (int i = t; i < DM; i += 256) { float v = xv[i]; s2 += v * v; }
            s2 = bs256(s2, red4);
            float inv2 = 1.f / sqrtf(s2 / DM + EPSV);
            const float* wpf = p.w_pf + (size_t)l * DM;
            for (int i = t; i < DM; i += 256) xv[i] = wpf[i] * xv[i] * inv2;
            __syncthreads();
            int f4c = t & 63, ks = t >> 6;
            int cgi = bid % 54, by = bid / 54;
            bool isU = cgi >= 27;
            int cg = isU ? cgi - 27 : cgi;
            const float4* W4 = (const float4*)((isU ? p.Wu : p.Wg) + (size_t)l * DM * FF);
            int colf4 = cg * 64 + f4c;
            int i0 = by * 64 + ks * 16;
            float4 w[16];
#pragma unroll
            for (int r = 0; r < 16; ++r) w[r] = W4[(size_t)(i0 + r) * 1728 + colf4];
            float4 acc = {0, 0, 0, 0};
#pragma unroll
            for (int r = 0; r < 16; ++r) {
                float xs = xv[i0 + r];
                acc.x += xs * w[r].x; acc.y += xs * w[r].y;
                acc.z += xs * w[r].z; acc.w += xs * w[r].w;
            }
            gred[t] = acc;
            __syncthreads();
            if (ks == 0) {
                float4 a = gred[f4c], b = gred[64 + f4c], c = gred[128 + f4c], d = gred[192 + f4c];
                float* dst = ws + GUP_O + (size_t)by * 13824 + (isU ? FF : 0) + 4 * colf4;
                dst[0] = a.x + b.x + c.x + d.x;
                dst[1] = a.y + b.y + c.y + d.y;
                dst[2] = a.z + b.z + c.z + d.z;
                dst[3] = a.w + b.w + c.w + d.w;
            }
        }
        gbar(gcl, gc, &ep);

        // ---------- wd phase (243 units) ----------
        if (bid < 243) {
            float* m = sm;                        // 256
            float4* wred = (float4*)(sm + 256);   // 256 f4
            const float* gup = ws + GUP_O;
            int bx = bid % 9, by = bid / 9;
            int i0 = by * 256;
            {
                float g = 0.f, u2 = 0.f;
#pragma unroll
                for (int p2 = 0; p2 < 18; ++p2) {
                    g += gup[(size_t)p2 * 13824 + i0 + t];
                    u2 += gup[(size_t)p2 * 13824 + FF + i0 + t];
                }
                float gl = 0.5f * g * (1.f + tanhf(0.7978845608028654f * (g + 0.044715f * g * g * g)));
                m[t] = gl * u2;
            }
            __syncthreads();
            int f4c = t & 31, ks = t >> 5;
            int col4 = bx * 32 + f4c;
            const float4* W4 = (const float4*)(p.Wd + (size_t)l * FF * DM);
            float4 acc = {0, 0, 0, 0};
#pragma unroll
            for (int bb = 0; bb < 2; ++bb) {
                int rb = ks * 32 + bb * 16;
                float4 w[16];
#pragma unroll
                for (int r = 0; r < 16; ++r) w[r] = W4[(size_t)(i0 + rb + r) * 288 + col4];
#pragma unroll
                for (int r = 0; r < 16; ++r) {
                    float xs = m[rb + r];
                    acc.x += xs * w[r].x; acc.y += xs * w[r].y;
                    acc.z += xs * w[r].z; acc.w += xs * w[r].w;
                }
            }
            wred[t] = acc;
            __syncthreads();
            if (t < 32) {
                float sx = 0, sy = 0, sz = 0, sw = 0;
#pragma unroll
                for (int k2 = 0; k2 < 8; ++k2) {
                    float4 r = wred[k2 * 32 + t];
                    sx += r.x; sy += r.y; sz += r.z; sw += r.w;
                }
                float* dst = ws + DPP_O + (size_t)by * DM + 4 * (bx * 32 + t);
                dst[0] = sx; dst[1] = sy; dst[2] = sz; dst[3] = sw;
            }
        }
        gbar(gcl, gc, &ep);
    }

    // ---------- logits phase (1024 units of 16 f4-cols) + fused argmax ----------
    {
        float* xv = sm; float* red4 = sm + 1152;
        float4* lred = (float4*)(sm + 1184);      // 256 f4
        unsigned long long* smu = (unsigned long long*)(sm + 2240);
        const float* dpp = ws + DPP_O;
        const float* hm5 = ws + HM_O;
        const float* wpof5 = p.w_pof + (size_t)5 * DM;
        for (int i = t; i < DM; i += 256) {
            float d = 0.f;
#pragma unroll
            for (int p2 = 0; p2 < 27; ++p2) d += dpp[p2 * DM + i];
            xv[i] = d;
        }
        float ss = 0.f;
        for (int i = t; i < DM; i += 256) { float d = xv[i]; ss += d * d; }
        ss = bs256(ss, red4);
        float inv = 1.f / sqrtf(ss / DM + EPSV);
        for (int i = t; i < DM; i += 256) xv[i] = hm5[i] + wpof5[i] * xv[i] * inv;
        float s2 = 0.f;
        for (int i = t; i < DM; i += 256) { float v = xv[i]; s2 += v * v; }
        s2 = bs256(s2, red4);
        float inv2 = 1.f / sqrtf(s2 / DM + EPSV);
        for (int i = t; i < DM; i += 256) xv[i] = p.w_fin[i] * xv[i] * inv2;
        __syncthreads();

        int f4c = t & 15, ks = t >> 4;           // 16 cols x 16 k-slices of 72 rows
        int colf4 = bid * 16 + f4c;
        const float4* W4 = (const float4*)p.Wlm;
        float4 acc = {0, 0, 0, 0};
#pragma unroll
        for (int bb = 0; bb < 6; ++bb) {
            int i0 = ks * 72 + bb * 12;
            float4 w[12];
#pragma unroll
            for (int r = 0; r < 12; ++r) w[r] = W4[(size_t)(i0 + r) * 16384 + colf4];
#pragma unroll
            for (int r = 0; r < 12; ++r) {
                float xs = xv[i0 + r];
                acc.x += xs * w[r].x; acc.y += xs * w[r].y;
                acc.z += xs * w[r].z; acc.w += xs * w[r].w;
            }
        }
        lred[t] = acc;
        __syncthreads();
        if (t < 16) {
            float sx = 0, sy = 0, sz = 0, sw = 0;
#pragma unroll
            for (int k2 = 0; k2 < 16; ++k2) {
                float4 r = lred[k2 * 16 + t];
                sx += r.x; sy += r.y; sz += r.z; sw += r.w;
            }
            float lv4[4] = {sx, sy, sz, sw};
            int c0 = bid * 64 + 4 * t;
            unsigned long long best = 0;
#pragma unroll
            for (int q = 0; q < 4; ++q) {
                unsigned bits = __float_as_uint(lv4[q]);
                unsigned key = (bits & 0x80000000u) ? ~bits : (bits | 0x80000000u);
                unsigned long long pk = ((unsigned long long)key << 32) | (unsigned)(~(c0 + q));
                if (pk > best) best = pk;
            }
            smu[t] = best;
        }
        __syncthreads();
        if (t == 0) {
            unsigned long long best = smu[0];
#pragma unroll
            for (int i = 1; i < 16; ++i) if (smu[i] > best) best = smu[i];
            unsigned long long* amx = (unsigned long long*)(ws + AMX_O);
            unsigned* cnt = (unsigned*)(ws + CNT_O);
            atomicMax(amx, best);
            __threadfence();
            if (atomicAdd(cnt, 1u) == (unsigned)(NB - 1)) {
                unsigned long long fin = atomicMax(amx, 0ull);
                p.tok[0] = (float)(~(unsigned)(fin & 0xFFFFFFFFull));
            }
        }
    }
}

// ==================== fallback: r13 verbatim (proven PASS 555) ====================
__device__ __forceinline__ float block_sum256(float v, float* red4) {
#pragma unroll
    for (int off = 32; off; off >>= 1) v += __shfl_xor(v, off);
    int t = threadIdx.x;
    if ((t & 63) == 0) red4[t >> 6] = v;
    __syncthreads();
    float r = red4[0] + red4[1] + red4[2] + red4[3];
    __syncthreads();
    return r;
}

__global__ __launch_bounds__(256) void gk_copy(
    const float* __restrict__ kc, const float* __restrict__ vc,
    float* __restrict__ keys, float* __restrict__ vals,
    const int* __restrict__ ids, const int* __restrict__ tbl,
    const float* __restrict__ esc, const float* __restrict__ ezp,
    const float* __restrict__ w_in0, float* __restrict__ hin0,
    float* __restrict__ xn0, unsigned int* __restrict__ cnts,
    unsigned long long* __restrict__ amx) {
    int b = blockIdx.x;
    int t = threadIdx.x;
    if (b < 24576) {
        int row = b >> 4;
        int s = ((b & 15) << 8) + t;
        if (s < HIST) keys[(size_t)row * SEQ + s] = kc[(size_t)row * HIST + s];
    } else {
        int r = (b - 24576) * 4 + (t >> 6);
        int d4 = t & 63;
        if (r < LNUM * HIST) {
            int l = r / HIST, sI = r - l * HIST;
            ((float4*)(vals + ((size_t)l * SEQ + sI) * DHEAD))[d4] =
                ((const float4*)(vc + (size_t)r * DHEAD))[d4];
        }
    }
    if (b == 0) {
        __shared__ float xv[DM];
        __shared__ float red4[4];
        int tok = ids[0];
        float sc = esc[tok], z = ezp[tok];
        const int* row = tbl + (size_t)tok * DM;
        for (int i = t; i < DM; i += 256) xv[i] = (float)row[i] * sc + z;
        for (int i = t; i < DM; i += 256) hin0[i] = xv[i];
        float ss = 0.f;
        for (int i = t; i < DM; i += 256) { float v = xv[i]; ss += v * v; }
        ss = block_sum256(ss, red4);
        float inv = 1.f / sqrtf(ss / DM + EPSV);
        for (int i = t; i < DM; i += 256) xn0[i] = w_in0[i] * xv[i] * inv;
        if (t < 16) cnts[t] = 0u;
        if (t == 0) *amx = 0ull;
    }
}

__global__ __launch_bounds__(256) void gk_qkv(
    const float* __restrict__ Wq, const float* __restrict__ Wk, const float* __restrict__ Wv,
    const float* __restrict__ wln, const float* __restrict__ wres,
    const float* __restrict__ hm_prev, const float* __restrict__ dpp,
    const float* __restrict__ xn0,
    float* __restrict__ hin_out, float* __restrict__ qkvp, int has_prev) {
    __shared__ float xv[DM];
    __shared__ float red4[4];
    __shared__ float4 qred[256];
    int t = threadIdx.x;
    if (has_prev) {
        for (int i = t; i < DM; i += 256) {
            float d = 0.f;
#pragma unroll
            for (int p2 = 0; p2 < 27; ++p2) d += dpp[p2 * DM + i];
            xv[i] = d;
        }
        float ss = 0.f;
        for (int i = t; i < DM; i += 256) { float d = xv[i]; ss += d * d; }
        ss = block_sum256(ss, red4);
        float inv = 1.f / sqrtf(ss / DM + EPSV);
        for (int i = t; i < DM; i += 256) xv[i] = hm_prev[i] + wres[i] * xv[i] * inv;
        if (blockIdx.x == 0 && blockIdx.y == 0)
            for (int i = t; i < DM; i += 256) hin_out[i] = xv[i];
        float s2 = 0.f;
        for (int i = t; i < DM; i += 256) { float v = xv[i]; s2 += v * v; }
        s2 = block_sum256(s2, red4);
        float inv2 = 1.f / sqrtf(s2 / DM + EPSV);
        for (int i = t; i < DM; i += 256) xv[i] = wln[i] * xv[i] * inv2;
    } else {
        for (int i = t; i < DM; i += 256) xv[i] = xn0[i];
    }
    __syncthreads();

    int f4c = t & 63, ks = t >> 6;
    int jf = blockIdx.x * 64 + f4c;
    const float4* W4; int jj4, ncol4;
    if (jf < 256)      { W4 = (const float4*)Wq; jj4 = jf;       ncol4 = 256; }
    else if (jf < 320) { W4 = (const float4*)Wk; jj4 = jf - 256; ncol4 = 64; }
    else               { W4 = (const float4*)Wv; jj4 = jf - 320; ncol4 = 64; }
    int i0 = blockIdx.y * 64 + ks * 16;
    float4 w[16];
#pragma unroll
    for (int r = 0; r < 16; ++r) w[r] = W4[(size_t)(i0 + r) * ncol4 + jj4];
    float4 acc = {0, 0, 0, 0};
#pragma unroll
    for (int r = 0; r < 16; ++r) {
        float xs = xv[i0 + r];
        acc.x += xs * w[r].x; acc.y += xs * w[r].y;
        acc.z += xs * w[r].z; acc.w += xs * w[r].w;
    }
    qred[t] = acc;
    __syncthreads();
    if (ks == 0) {
        float4 a = qred[f4c], b = qred[64 + f4c], c = qred[128 + f4c], d = qred[192 + f4c];
        float* dst = qkvp + (size_t)blockIdx.y * 1536 + 4 * jf;
        dst[0] = a.x + b.x + c.x + d.x;
        dst[1] = a.y + b.y + c.y + d.y;
        dst[2] = a.z + b.z + c.z + d.z;
        dst[3] = a.w + b.w + c.w + d.w;
    }
}

__global__ __launch_bounds__(256) void gk_attn(
    const float* __restrict__ qkvp, const float* __restrict__ w_qn,
    const float* __restrict__ w_kn, const int* __restrict__ attn_flag,
    float* __restrict__ keys_l, float* __restrict__ vals_l,
    float* __restrict__ po_part, float* __restrict__ sum_part, float rope_base) {
    __shared__ float lq[NH * DHEAD];
    __shared__ float lqf[NH * DHEAD];
    __shared__ float lkn[DHEAD];
    __shared__ float lkf[DHEAD];
    __shared__ float lv[DHEAD];
    __shared__ float lp[NH * 32];
    int t = threadIdx.x;
    int s0 = blockIdx.x * 32;
    bool last = (blockIdx.x == gridDim.x - 1);

    int jm = t & 127;
    float theta = powf(rope_base, -(float)(2 * jm) / 256.f);
    float ang = 4095.f * theta;
    float c = __half2float(__float2half(cosf(ang)));
    float s = __half2float(__float2half(sinf(ang)));

    for (int j = t; j < 1536; j += 256) {
        float v = 0.f;
#pragma unroll
        for (int p2 = 0; p2 < 18; ++p2) v += qkvp[p2 * 1536 + j];
        if (j < 1024) lq[j] = v;
        else if (j < 1280) lkn[j - 1024] = v;
        else lv[j - 1280] = v;
    }
    __syncthreads();
    int wv = t >> 6, ln = t & 63;
    float sq = 0.f, sk = 0.f;
#pragma unroll
    for (int j = 0; j < 4; ++j) {
        float v = lq[wv * 256 + j * 64 + ln]; sq += v * v;
        float u = lkn[j * 64 + ln];           sk += u * u;
    }
#pragma unroll
    for (int off = 32; off; off >>= 1) { sq += __shfl_xor(sq, off); sk += __shfl_xor(sk, off); }
    float invq = 1.f / sqrtf(sq / 256.f + EPSV);
    float invk = 1.f / sqrtf(sk / 256.f + EPSV);
    __syncthreads();
#pragma unroll
    for (int j = 0; j < 4; ++j) {
        int d = j * 64 + ln;
        lq[wv * 256 + d] *= w_qn[d] * invq;
        if (wv == 0) lkn[d] *= w_kn[d] * invk;
    }
    __syncthreads();
    {
        float kn = lkn[t];
        float prk = (t < 128) ? -lkn[t + 128] : lkn[t - 128];
        lkf[t] = kn * c + prk * s;
#pragma unroll
        for (int h = 0; h < NH; ++h) {
            float qn = lq[h * 256 + t];
            float pr = (t < 128) ? -lq[h * 256 + t + 128] : lq[h * 256 + t - 128];
            lqf[h * 256 + t] = qn * c + pr * s;
        }
    }
    __syncthreads();
    if (last) {
        keys_l[(size_t)t * SEQ + (SEQ - 1)] = lkf[t];
        vals_l[(size_t)(SEQ - 1) * DHEAD + t] = lv[t];
    }
    int sl = t & 31, dc = t >> 5;
    int sg = s0 + sl;
    bool self = last && (sl == 31);
    float a0 = 0, a1 = 0, a2 = 0, a3 = 0;
#pragma unroll 4
    for (int dd = 0; dd < 32; ++dd) {
        int d = dc * 32 + dd;
        float kv = self ? lkf[d] : keys_l[(size_t)d * SEQ + sg];
        a0 += lqf[0 * 256 + d] * kv;
        a1 += lqf[1 * 256 + d] * kv;
        a2 += lqf[2 * 256 + d] * kv;
        a3 += lqf[3 * 256 + d] * kv;
    }
    __syncthreads();
    lq[0 * 256 + t] = a0; lq[1 * 256 + t] = a1; lq[2 * 256 + t] = a2; lq[3 * 256 + t] = a3;
    __syncthreads();
    if (t < 32) {
        int af = attn_flag[0];
        float mk = (s0 + t > 0) ? -128.f * (float)af : 0.f;
        for (int h = 0; h < NH; ++h) {
            float sc_ = 0.f;
#pragma unroll
            for (int d8 = 0; d8 < 8; ++d8) sc_ += lq[h * 256 + d8 * 32 + t];
            lp[h * 32 + t] = expf(sc_ + mk);
        }
    }
    __syncthreads();
    if (t < NH) {
        float su = 0.f;
        for (int i = 0; i < 32; ++i) su += lp[t * 32 + i];
        sum_part[blockIdx.x * NH + t] = su;
    }
    float p0 = 0, p1 = 0, p2 = 0, p3 = 0;
#pragma unroll 4
    for (int ss_ = 0; ss_ < 32; ++ss_) {
        float v = (last && ss_ == 31) ? lv[t] : vals_l[(size_t)(s0 + ss_) * DHEAD + t];
        p0 += lp[0 * 32 + ss_] * v;
        p1 += lp[1 * 32 + ss_] * v;
        p2 += lp[2 * 32 + ss_] * v;
        p3 += lp[3 * 32 + ss_] * v;
    }
    float* po = po_part + (size_t)blockIdx.x * NH * DHEAD;
    po[0 * 256 + t] = p0; po[1 * 256 + t] = p1; po[2 * 256 + t] = p2; po[3 * 256 + t] = p3;
}

__global__ __launch_bounds__(256) void gk_wo(
    const float* __restrict__ po_part, const float* __restrict__ sum_part,
    const float* __restrict__ Wo_l, float* __restrict__ app) {
    __shared__ float x[64];
    __shared__ float hinv[NH];
    __shared__ float red4[4];
    int t = threadIdx.x;
    for (int h = 0; h < NH; ++h) {
        float v = (t < 128) ? sum_part[t * NH + h] : 0.f;
        float tot = block_sum256(v, red4);
        if (t == 0) hinv[h] = 1.f / tot;
    }
    __syncthreads();
    int i0 = blockIdx.y * 64;
    if (t < 64) {
        float a = 0.f;
#pragma unroll 8
        for (int b = 0; b < 128; ++b) a += po_part[(size_t)b * 1024 + i0 + t];
        x[t] = a * hinv[(i0 + t) >> 8];
    }
    __syncthreads();
    int j = blockIdx.x * 256 + t;
    if (j < DM) {
        float acc = 0.f;
#pragma unroll 4
        for (int ii = 0; ii < 64; ++ii)
            acc += x[ii] * Wo_l[(size_t)(i0 + ii) * DM + j];
        app[(size_t)blockIdx.y * DM + j] = acc;
    }
}

__global__ __launch_bounds__(256) void gk_gu(
    const float* __restrict__ Wg_l, const float* __restrict__ Wu_l,
    const float* __restrict__ w_pa, const float* __restrict__ w_pf,
    const float* __restrict__ hin, const float* __restrict__ app,
    float* __restrict__ hm_out, float* __restrict__ gup) {
    __shared__ float xv[DM];
    __shared__ float red4[4];
    __shared__ float4 gred[256];
    int t = threadIdx.x;
    for (int i = t; i < DM; i += 256) {
        float a = 0.f;
#pragma unroll
        for (int p2 = 0; p2 < 16; ++p2) a += app[p2 * DM + i];
        xv[i] = a;
    }
    float ss = 0.f;
    for (int i = t; i < DM; i += 256) { float a = xv[i]; ss += a * a; }
    ss = block_sum256(ss, red4);
    float inv = 1.f / sqrtf(ss / DM + EPSV);
    for (int i = t; i < DM; i += 256) xv[i] = hin[i] + w_pa[i] * xv[i] * inv;
    if (blockIdx.x == 0 && blockIdx.y == 0)
        for (int i = t; i < DM; i += 256) hm_out[i] = xv[i];
    float s2 = 0.f;
    for (int i = t; i < DM; i += 256) { float v = xv[i]; s2 += v * v; }
    s2 = block_sum256(s2, red4);
    float inv2 = 1.f / sqrtf(s2 / DM + EPSV);
    for (int i = t; i < DM; i += 256) xv[i] = w_pf[i] * xv[i] * inv2;
    __syncthreads();

    int f4c = t & 63, ks = t >> 6;
    int cgi = blockIdx.x;
    bool isU = cgi >= 27;
    int cg = isU ? cgi - 27 : cgi;
    const float4* W4 = (const float4*)(isU ? Wu_l : Wg_l);
    int colf4 = cg * 64 + f4c;
    int i0 = blockIdx.y * 64 + ks * 16;
    float4 w[16];
#pragma unroll
    for (int r = 0; r < 16; ++r) w[r] = W4[(size_t)(i0 + r) * 1728 + colf4];
    float4 acc = {0, 0, 0, 0};
#pragma unroll
    for (int r = 0; r < 16; ++r) {
        float xs = xv[i0 + r];
        acc.x += xs * w[r].x; acc.y += xs * w[r].y;
        acc.z += xs * w[r].z; acc.w += xs * w[r].w;
    }
    gred[t] = acc;
    __syncthreads();
    if (ks == 0) {
        float4 a = gred[f4c], b = gred[64 + f4c], c = gred[128 + f4c], d = gred[192 + f4c];
        float* dst = gup + (size_t)blockIdx.y * 13824 + (isU ? FF : 0) + 4 * colf4;
        dst[0] = a.x + b.x + c.x + d.x;
        dst[1] = a.y + b.y + c.y + d.y;
        dst[2] = a.z + b.z + c.z + d.z;
        dst[3] = a.w + b.w + c.w + d.w;
    }
}

__global__ __launch_bounds__(256) void gk_wd(const float* __restrict__ gup,
                                             const float* __restrict__ Wd_l,
                                             float* __restrict__ dpp) {
    __shared__ float m[256];
    __shared__ float4 wred[256];
    int t = threadIdx.x;
    int i0 = blockIdx.y * 256;
    {
        float g = 0.f, u = 0.f;
#pragma unroll
        for (int p2 = 0; p2 < 18; ++p2) {
            g += gup[(size_t)p2 * 13824 + i0 + t];
            u += gup[(size_t)p2 * 13824 + FF + i0 + t];
        }
        float gl = 0.5f * g * (1.f + tanhf(0.7978845608028654f * (g + 0.044715f * g * g * g)));
        m[t] = gl * u;
    }
    __syncthreads();
    int f4c = t & 31, ks = t >> 5;
    int col4 = blockIdx.x * 32 + f4c;
    const float4* W4 = (const float4*)Wd_l;
    float4 acc = {0, 0, 0, 0};
#pragma unroll
    for (int bb = 0; bb < 2; ++bb) {
        int rb = ks * 32 + bb * 16;
        float4 w[16];
#pragma unroll
        for (int r = 0; r < 16; ++r) w[r] = W4[(size_t)(i0 + rb + r) * 288 + col4];
#pragma unroll
        for (int r = 0; r < 16; ++r) {
            float xs = m[rb + r];
            acc.x += xs * w[r].x; acc.y += xs * w[r].y;
            acc.z += xs * w[r].z; acc.w += xs * w[r].w;
        }
    }
    wred[t] = acc;
    __syncthreads();
    if (t < 32) {
        float sx = 0, sy = 0, sz = 0, sw = 0;
#pragma unroll
        for (int k2 = 0; k2 < 8; ++k2) {
            float4 r = wred[k2 * 32 + t];
            sx += r.x; sy += r.y; sz += r.z; sw += r.w;
        }
        float* dst = dpp + (size_t)blockIdx.y * DM + 4 * (blockIdx.x * 32 + t);
        dst[0] = sx; dst[1] = sy; dst[2] = sz; dst[3] = sw;
    }
}

__global__ __launch_bounds__(256) void gk_logits(
    const float* __restrict__ W_lm,
    const float* __restrict__ hm5, const float* __restrict__ dpp,
    const float* __restrict__ wpof5, const float* __restrict__ wfin,
    unsigned long long* __restrict__ amx, unsigned int* __restrict__ cnt,
    float* __restrict__ tok_out) {
    __shared__ float xv[DM];
    __shared__ float red4[4];
    __shared__ float4 lred[256];
    __shared__ unsigned long long smu[64];
    int t = threadIdx.x;
    for (int i = t; i < DM; i += 256) {
        float d = 0.f;
#pragma unroll
        for (int p2 = 0; p2 < 27; ++p2) d += dpp[p2 * DM + i];
        xv[i] = d;
    }
    float ss = 0.f;
    for (int i = t; i < DM; i += 256) { float d = xv[i]; ss += d * d; }
    ss = block_sum256(ss, red4);
    float inv = 1.f / sqrtf(ss / DM + EPSV);
    for (int i = t; i < DM; i += 256) xv[i] = hm5[i] + wpof5[i] * xv[i] * inv;
    float s2 = 0.f;
    for (int i = t; i < DM; i += 256) { float v = xv[i]; s2 += v * v; }
    s2 = block_sum256(s2, red4);
    float inv2 = 1.f / sqrtf(s2 / DM + EPSV);
    for (int i = t; i < DM; i += 256) xv[i] = wfin[i] * xv[i] * inv2;
    __syncthreads();

    int f4c = t & 63, ks = t >> 6;
    int colf4 = blockIdx.x * 64 + f4c;
    const float4* W4 = (const float4*)W_lm;
    float4 acc = {0, 0, 0, 0};
    for (int bb = 0; bb < 18; ++bb) {
        int i0 = ks * 288 + bb * 16;
        float4 w[16];
#pragma unroll
        for (int r = 0; r < 16; ++r) w[r] = W4[(size_t)(i0 + r) * 16384 + colf4];
#pragma unroll
        for (int r = 0; r < 16; ++r) {
            float xs = xv[i0 + r];
            acc.x += xs * w[r].x; acc.y += xs * w[r].y;
            acc.z += xs * w[r].z; acc.w += xs * w[r].w;
        }
    }
    lred[t] = acc;
    __syncthreads();
    if (ks == 0) {
        float4 a = lred[f4c], b = lred[64 + f4c], c = lred[128 + f4c], d = lred[192 + f4c];
        float lv[4] = { a.x + b.x + c.x + d.x, a.y + b.y + c.y + d.y,
                        a.z + b.z + c.z + d.z, a.w + b.w + c.w + d.w };
        int c0 = blockIdx.x * 256 + 4 * f4c;
        unsigned long long best = 0;
#pragma unroll
        for (int q = 0; q < 4; ++q) {
            unsigned bits = __float_as_uint(lv[q]);
            unsigned key = (bits & 0x80000000u) ? ~bits : (bits | 0x80000000u);
            unsigned long long pk = ((unsigned long long)key << 32) | (unsigned)(~(c0 + q));
            if (pk > best) best = pk;
        }
        smu[f4c] = best;
    }
    __syncthreads();
    for (int off = 32; off; off >>= 1) {
        if (t < off) { if (smu[t + off] > smu[t]) smu[t] = smu[t + off]; }
        __syncthreads();
    }
    if (t == 0) {
        atomicMax(amx, smu[0]);
        __threadfence();
        if (atomicAdd(cnt, 1u) == 255u) {
            unsigned long long fin = atomicMax(amx, 0ull);
            tok_out[0] = (float)(~(unsigned)(fin & 0xFFFFFFFFull));
        }
    }
}

// ==================== host launcher ====================
extern "C" void kernel_launch(void* const* d_in, const int* in_sizes, int n_in,
                              void* d_out, int out_size, void* d_ws, size_t ws_size,
                              hipStream_t stream) {
    P p;
    p.ids   = (const int*)d_in[0];
    p.aflag = (const int*)d_in[1];
    p.kc    = (const float*)d_in[2];
    p.vc    = (const float*)d_in[3];
    p.tbl   = (const int*)d_in[4];
    p.esc   = (const float*)d_in[5];
    p.ezp   = (const float*)d_in[6];
    p.w_in  = (const float*)d_in[7];
    p.w_qn  = (const float*)d_in[8];
    p.w_kn  = (const float*)d_in[9];
    p.Wq    = (const float*)d_in[10];
    p.Wk    = (const float*)d_in[11];
    p.Wv    = (const float*)d_in[12];
    p.Wo    = (const float*)d_in[13];
    p.w_pa  = (const float*)d_in[14];
    p.w_pf  = (const float*)d_in[15];
    p.w_pof = (const float*)d_in[16];
    p.Wg    = (const float*)d_in[17];
    p.Wu    = (const float*)d_in[18];
    p.Wd    = (const float*)d_in[19];
    p.w_fin = (const float*)d_in[20];
    p.Wlm   = (const float*)d_in[21];
    p.keys  = (float*)d_out;
    p.vals  = p.keys + (size_t)LNUM * DHEAD * SEQ;
    p.tok   = p.vals + (size_t)LNUM * SEQ * DHEAD;
    p.ws    = (float*)d_ws;
    float* ws = (float*)d_ws;

    // zero barrier + argmax state (both paths tolerate this)
    hipMemsetAsync(ws + AMX_O, 0, (INIT_END - AMX_O) * sizeof(float), stream);

    void* args[] = { &p };
    hipError_t err = hipLaunchCooperativeKernel((void*)mega, dim3(NB), dim3(256), args, 0, stream);

    if (err != hipSuccess) {
        // fallback: r13 multi-kernel path (proven PASS)
        unsigned int* cnts = (unsigned int*)(ws + CNT_O);
        unsigned long long* amx = (unsigned long long*)(ws + AMX_O);
        gk_copy<<<24576 + 6144, 256, 0, stream>>>(
            p.kc, p.vc, p.keys, p.vals, p.ids, p.tbl, p.esc, p.ezp,
            p.w_in, ws + HIN_O, ws + XN0_O, cnts, amx);
        for (int l = 0; l < LNUM; ++l) {
            float* keys_l = p.keys + (size_t)l * DHEAD * SEQ;
            float* vals_l = p.vals + (size_t)l * SEQ * DHEAD;
            gk_qkv<<<dim3(6, 18), 256, 0, stream>>>(
                p.Wq + (size_t)l * DM * 1024, p.Wk + (size_t)l * DM * 256,
                p.Wv + (size_t)l * DM * 256,
                p.w_in + (size_t)l * DM,
                (l ? p.w_pof + (size_t)(l - 1) * DM : p.w_in),
                ws + HM_O, ws + DPP_O, ws + XN0_O,
                ws + HIN_O, ws + QKVP_O, (l > 0) ? 1 : 0);
            gk_attn<<<128, 256, 0, stream>>>(
                ws + QKVP_O, p.w_qn + (size_t)l * DHEAD, p.w_kn + (size_t)l * DHEAD,
                p.aflag, keys_l, vals_l, ws + POP_O, ws + SPS_O,
                ((l % 6) != 5) ? 1000000.0f : 10000.0f);
            gk_wo<<<dim3(5, 16), 256, 0, stream>>>(
                ws + POP_O, ws + SPS_O, p.Wo + (size_t)l * 1024 * DM, ws + APP_O);
            gk_gu<<<dim3(54, 18), 256, 0, stream>>>(
                p.Wg + (size_t)l * DM * FF, p.Wu + (size_t)l * DM * FF,
                p.w_pa + (size_t)l * DM, p.w_pf + (size_t)l * DM,
                ws + HIN_O, ws + APP_O, ws + HM_O, ws + GUP_O);
            gk_wd<<<dim3(9, 27), 256, 0, stream>>>(
                ws + GUP_O, p.Wd + (size_t)l * FF * DM, ws + DPP_O);
        }
        gk_logits<<<256, 256, 0, stream>>>(
            p.Wlm, ws + HM_O, ws + DPP_O,
            p.w_pof + (size_t)5 * DM, p.w_fin, amx, (unsigned*)(ws + CNT_O), p.tok);
    }
}

// Round 15
// 562.593 us; speedup vs baseline: 35.5737x; 35.5737x over previous
//
#include <hip/hip_runtime.h>
#include <hip/hip_fp16.h>
#include <cmath>

#define LNUM 6
#define DM   1152
#define DHEAD 256
#define NH   4
#define FF   6912
#define VOC  65536
#define HIST 4095
#define SEQ  4096
#define EPSV 1e-6f

// ---- ws float offsets (all regions fully overwritten before read, every call) ----
#define POP_O   0          // [128][1024]
#define SPS_O   131072     // [128][4]
#define QKVP_O  131584     // [18][1536]
#define APP_O   159232     // [16][1152]
#define DPP_O   177664     // [27][1152]
#define GUP_O   208768     // [18][13824]
#define HIN_O   457600     // [1152]
#define HM_O    458752     // [1152]
#define XN0_O   459904     // [1152]
#define AMX_O   461056     // u64 (8B aligned)
#define CNT_O   461058     // [16] u32

__device__ __forceinline__ float block_sum256(float v, float* red4) {
#pragma unroll
    for (int off = 32; off; off >>= 1) v += __shfl_xor(v, off);
    int t = threadIdx.x;
    if ((t & 63) == 0) red4[t >> 6] = v;
    __syncthreads();
    float r = red4[0] + red4[1] + red4[2] + red4[3];
    __syncthreads();
    return r;
}

// ---------------- cache copies + embed + first RMS + counter init ----------------
__global__ __launch_bounds__(256) void gk_copy(
    const float* __restrict__ kc, const float* __restrict__ vc,
    float* __restrict__ keys, float* __restrict__ vals,
    const int* __restrict__ ids, const int* __restrict__ tbl,
    const float* __restrict__ esc, const float* __restrict__ ezp,
    const float* __restrict__ w_in0, float* __restrict__ hin0,
    float* __restrict__ xn0, unsigned int* __restrict__ cnts,
    unsigned long long* __restrict__ amx) {
    int b = blockIdx.x;
    int t = threadIdx.x;
    if (b < 24576) {
        int row = b >> 4;
        int s = ((b & 15) << 8) + t;
        if (s < HIST) keys[(size_t)row * SEQ + s] = kc[(size_t)row * HIST + s];
    } else {
        int r = (b - 24576) * 4 + (t >> 6);
        int d4 = t & 63;
        if (r < LNUM * HIST) {
            int l = r / HIST, sI = r - l * HIST;
            ((float4*)(vals + ((size_t)l * SEQ + sI) * DHEAD))[d4] =
                ((const float4*)(vc + (size_t)r * DHEAD))[d4];
        }
    }
    if (b == 0) {
        __shared__ float xv[DM];
        __shared__ float red4[4];
        int tok = ids[0];
        float sc = esc[tok], z = ezp[tok];
        const int* row = tbl + (size_t)tok * DM;
        for (int i = t; i < DM; i += 256) xv[i] = (float)row[i] * sc + z;
        for (int i = t; i < DM; i += 256) hin0[i] = xv[i];
        float ss = 0.f;
        for (int i = t; i < DM; i += 256) { float v = xv[i]; ss += v * v; }
        ss = block_sum256(ss, red4);
        float inv = 1.f / sqrtf(ss / DM + EPSV);
        for (int i = t; i < DM; i += 256) xn0[i] = w_in0[i] * xv[i] * inv;
        if (t < 16) cnts[t] = 0u;
        if (t == 0) *amx = 0ull;
    }
}

// ---------------- qkv: redundant prefix (reduce DPP[27] + residual + 2xRMS) + GEMV ----------------
__global__ __launch_bounds__(256) void gk_qkv(
    const float* __restrict__ Wq, const float* __restrict__ Wk, const float* __restrict__ Wv,
    const float* __restrict__ wln, const float* __restrict__ wres,
    const float* __restrict__ hm_prev, const float* __restrict__ dpp,
    const float* __restrict__ xn0,
    float* __restrict__ hin_out, float* __restrict__ qkvp, int has_prev) {
    __shared__ float xv[DM];
    __shared__ float red4[4];
    __shared__ float4 qred[256];
    int t = threadIdx.x;
    if (has_prev) {
        for (int i = t; i < DM; i += 256) {
            float d = 0.f;
#pragma unroll
            for (int p2 = 0; p2 < 27; ++p2) d += dpp[p2 * DM + i];
            xv[i] = d;
        }
        float ss = 0.f;
        for (int i = t; i < DM; i += 256) { float d = xv[i]; ss += d * d; }
        ss = block_sum256(ss, red4);
        float inv = 1.f / sqrtf(ss / DM + EPSV);
        for (int i = t; i < DM; i += 256) xv[i] = hm_prev[i] + wres[i] * xv[i] * inv;
        if (blockIdx.x == 0 && blockIdx.y == 0)
            for (int i = t; i < DM; i += 256) hin_out[i] = xv[i];
        float s2 = 0.f;
        for (int i = t; i < DM; i += 256) { float v = xv[i]; s2 += v * v; }
        s2 = block_sum256(s2, red4);
        float inv2 = 1.f / sqrtf(s2 / DM + EPSV);
        for (int i = t; i < DM; i += 256) xv[i] = wln[i] * xv[i] * inv2;
    } else {
        for (int i = t; i < DM; i += 256) xv[i] = xn0[i];
    }
    __syncthreads();

    int f4c = t & 63, ks = t >> 6;
    int jf = blockIdx.x * 64 + f4c;          // 0..383
    const float4* W4; int jj4, ncol4;
    if (jf < 256)      { W4 = (const float4*)Wq; jj4 = jf;       ncol4 = 256; }
    else if (jf < 320) { W4 = (const float4*)Wk; jj4 = jf - 256; ncol4 = 64; }
    else               { W4 = (const float4*)Wv; jj4 = jf - 320; ncol4 = 64; }
    int i0 = blockIdx.y * 64 + ks * 16;
    float4 w[16];
#pragma unroll
    for (int r = 0; r < 16; ++r) w[r] = W4[(size_t)(i0 + r) * ncol4 + jj4];
    float4 acc = {0, 0, 0, 0};
#pragma unroll
    for (int r = 0; r < 16; ++r) {
        float xs = xv[i0 + r];
        acc.x += xs * w[r].x; acc.y += xs * w[r].y;
        acc.z += xs * w[r].z; acc.w += xs * w[r].w;
    }
    qred[t] = acc;
    __syncthreads();
    if (ks == 0) {
        float4 a = qred[f4c], b = qred[64 + f4c], c = qred[128 + f4c], d = qred[192 + f4c];
        float* dst = qkvp + (size_t)blockIdx.y * 1536 + 4 * jf;
        dst[0] = a.x + b.x + c.x + d.x;
        dst[1] = a.y + b.y + c.y + d.y;
        dst[2] = a.z + b.z + c.z + d.z;
        dst[3] = a.w + b.w + c.w + d.w;
    }
}

// ---------------- fused attention (inline QKVP reduce; proven) ----------------
__global__ __launch_bounds__(256) void gk_attn(
    const float* __restrict__ qkvp, const float* __restrict__ w_qn,
    const float* __restrict__ w_kn, const int* __restrict__ attn_flag,
    float* __restrict__ keys_l, float* __restrict__ vals_l,
    float* __restrict__ po_part, float* __restrict__ sum_part, float rope_base) {
    __shared__ float lq[NH * DHEAD];
    __shared__ float lqf[NH * DHEAD];
    __shared__ float lkn[DHEAD];
    __shared__ float lkf[DHEAD];
    __shared__ float lv[DHEAD];
    __shared__ float lp[NH * 32];
    int t = threadIdx.x;
    int s0 = blockIdx.x * 32;
    bool last = (blockIdx.x == gridDim.x - 1);

    int jm = t & 127;
    float theta = powf(rope_base, -(float)(2 * jm) / 256.f);
    float ang = 4095.f * theta;
    float c = __half2float(__float2half(cosf(ang)));
    float s = __half2float(__float2half(sinf(ang)));

    for (int j = t; j < 1536; j += 256) {
        float v = 0.f;
#pragma unroll
        for (int p2 = 0; p2 < 18; ++p2) v += qkvp[p2 * 1536 + j];
        if (j < 1024) lq[j] = v;
        else if (j < 1280) lkn[j - 1024] = v;
        else lv[j - 1280] = v;
    }
    __syncthreads();
    int wv = t >> 6, ln = t & 63;
    float sq = 0.f, sk = 0.f;
#pragma unroll
    for (int j = 0; j < 4; ++j) {
        float v = lq[wv * 256 + j * 64 + ln]; sq += v * v;
        float u = lkn[j * 64 + ln];           sk += u * u;
    }
#pragma unroll
    for (int off = 32; off; off >>= 1) { sq += __shfl_xor(sq, off); sk += __shfl_xor(sk, off); }
    float invq = 1.f / sqrtf(sq / 256.f + EPSV);
    float invk = 1.f / sqrtf(sk / 256.f + EPSV);
    __syncthreads();
#pragma unroll
    for (int j = 0; j < 4; ++j) {
        int d = j * 64 + ln;
        lq[wv * 256 + d] *= w_qn[d] * invq;
        if (wv == 0) lkn[d] *= w_kn[d] * invk;
    }
    __syncthreads();
    {
        float kn = lkn[t];
        float prk = (t < 128) ? -lkn[t + 128] : lkn[t - 128];
        lkf[t] = kn * c + prk * s;
#pragma unroll
        for (int h = 0; h < NH; ++h) {
            float qn = lq[h * 256 + t];
            float pr = (t < 128) ? -lq[h * 256 + t + 128] : lq[h * 256 + t - 128];
            lqf[h * 256 + t] = qn * c + pr * s;
        }
    }
    __syncthreads();
    if (last) {
        keys_l[(size_t)t * SEQ + (SEQ - 1)] = lkf[t];
        vals_l[(size_t)(SEQ - 1) * DHEAD + t] = lv[t];
    }
    int sl = t & 31, dc = t >> 5;
    int sg = s0 + sl;
    bool self = last && (sl == 31);
    float a0 = 0, a1 = 0, a2 = 0, a3 = 0;
#pragma unroll 4
    for (int dd = 0; dd < 32; ++dd) {
        int d = dc * 32 + dd;
        float kv = self ? lkf[d] : keys_l[(size_t)d * SEQ + sg];
        a0 += lqf[0 * 256 + d] * kv;
        a1 += lqf[1 * 256 + d] * kv;
        a2 += lqf[2 * 256 + d] * kv;
        a3 += lqf[3 * 256 + d] * kv;
    }
    __syncthreads();
    lq[0 * 256 + t] = a0; lq[1 * 256 + t] = a1; lq[2 * 256 + t] = a2; lq[3 * 256 + t] = a3;
    __syncthreads();
    if (t < 32) {
        int af = attn_flag[0];
        float mk = (s0 + t > 0) ? -128.f * (float)af : 0.f;
        for (int h = 0; h < NH; ++h) {
            float sc_ = 0.f;
#pragma unroll
            for (int d8 = 0; d8 < 8; ++d8) sc_ += lq[h * 256 + d8 * 32 + t];
            lp[h * 32 + t] = expf(sc_ + mk);
        }
    }
    __syncthreads();
    if (t < NH) {
        float su = 0.f;
        for (int i = 0; i < 32; ++i) su += lp[t * 32 + i];
        sum_part[blockIdx.x * NH + t] = su;
    }
    float p0 = 0, p1 = 0, p2 = 0, p3 = 0;
#pragma unroll 4
    for (int ss_ = 0; ss_ < 32; ++ss_) {
        float v = (last && ss_ == 31) ? lv[t] : vals_l[(size_t)(s0 + ss_) * DHEAD + t];
        p0 += lp[0 * 32 + ss_] * v;
        p1 += lp[1 * 32 + ss_] * v;
        p2 += lp[2 * 32 + ss_] * v;
        p3 += lp[3 * 32 + ss_] * v;
    }
    float* po = po_part + (size_t)blockIdx.x * NH * DHEAD;
    po[0 * 256 + t] = p0; po[1 * 256 + t] = p1; po[2 * 256 + t] = p2; po[3 * 256 + t] = p3;
}

// ---------------- wo -> APP partials, grid(5,16) (proven) ----------------
__global__ __launch_bounds__(256) void gk_wo(
    const float* __restrict__ po_part, const float* __restrict__ sum_part,
    const float* __restrict__ Wo_l, float* __restrict__ app) {
    __shared__ float x[64];
    __shared__ float hinv[NH];
    __shared__ float red4[4];
    int t = threadIdx.x;
    for (int h = 0; h < NH; ++h) {
        float v = (t < 128) ? sum_part[t * NH + h] : 0.f;
        float tot = block_sum256(v, red4);
        if (t == 0) hinv[h] = 1.f / tot;
    }
    __syncthreads();
    int i0 = blockIdx.y * 64;
    if (t < 64) {
        float a = 0.f;
#pragma unroll 8
        for (int b = 0; b < 128; ++b) a += po_part[(size_t)b * 1024 + i0 + t];
        x[t] = a * hinv[(i0 + t) >> 8];
    }
    __syncthreads();
    int j = blockIdx.x * 256 + t;
    if (j < DM) {
        float acc = 0.f;
#pragma unroll 4
        for (int ii = 0; ii < 64; ++ii)
            acc += x[ii] * Wo_l[(size_t)(i0 + ii) * DM + j];
        app[(size_t)blockIdx.y * DM + j] = acc;
    }
}

// ---------------- gu: redundant prefix (reduce APP[16] + residual + 2xRMS) + GEMV ----------------
__global__ __launch_bounds__(256) void gk_gu(
    const float* __restrict__ Wg_l, const float* __restrict__ Wu_l,
    const float* __restrict__ w_pa, const float* __restrict__ w_pf,
    const float* __restrict__ hin, const float* __restrict__ app,
    float* __restrict__ hm_out, float* __restrict__ gup) {
    __shared__ float xv[DM];
    __shared__ float red4[4];
    __shared__ float4 gred[256];
    int t = threadIdx.x;
    for (int i = t; i < DM; i += 256) {
        float a = 0.f;
#pragma unroll
        for (int p2 = 0; p2 < 16; ++p2) a += app[p2 * DM + i];
        xv[i] = a;
    }
    float ss = 0.f;
    for (int i = t; i < DM; i += 256) { float a = xv[i]; ss += a * a; }
    ss = block_sum256(ss, red4);
    float inv = 1.f / sqrtf(ss / DM + EPSV);
    for (int i = t; i < DM; i += 256) xv[i] = hin[i] + w_pa[i] * xv[i] * inv;
    if (blockIdx.x == 0 && blockIdx.y == 0)
        for (int i = t; i < DM; i += 256) hm_out[i] = xv[i];
    float s2 = 0.f;
    for (int i = t; i < DM; i += 256) { float v = xv[i]; s2 += v * v; }
    s2 = block_sum256(s2, red4);
    float inv2 = 1.f / sqrtf(s2 / DM + EPSV);
    for (int i = t; i < DM; i += 256) xv[i] = w_pf[i] * xv[i] * inv2;
    __syncthreads();

    int f4c = t & 63, ks = t >> 6;
    int cgi = blockIdx.x;
    bool isU = cgi >= 27;
    int cg = isU ? cgi - 27 : cgi;
    const float4* W4 = (const float4*)(isU ? Wu_l : Wg_l);
    int colf4 = cg * 64 + f4c;
    int i0 = blockIdx.y * 64 + ks * 16;
    float4 w[16];
#pragma unroll
    for (int r = 0; r < 16; ++r) w[r] = W4[(size_t)(i0 + r) * 1728 + colf4];
    float4 acc = {0, 0, 0, 0};
#pragma unroll
    for (int r = 0; r < 16; ++r) {
        float xs = xv[i0 + r];
        acc.x += xs * w[r].x; acc.y += xs * w[r].y;
        acc.z += xs * w[r].z; acc.w += xs * w[r].w;
    }
    gred[t] = acc;
    __syncthreads();
    if (ks == 0) {
        float4 a = gred[f4c], b = gred[64 + f4c], c = gred[128 + f4c], d = gred[192 + f4c];
        float* dst = gup + (size_t)blockIdx.y * 13824 + (isU ? FF : 0) + 4 * colf4;
        dst[0] = a.x + b.x + c.x + d.x;
        dst[1] = a.y + b.y + c.y + d.y;
        dst[2] = a.z + b.z + c.z + d.z;
        dst[3] = a.w + b.w + c.w + d.w;
    }
}

// ---------------- wd: reduce GUP + gelu + GEMV -> DPP[27] partials, grid(18,27) ----------------
__global__ __launch_bounds__(256) void gk_wd(const float* __restrict__ gup,
                                             const float* __restrict__ Wd_l,
                                             float* __restrict__ dpp) {
    __shared__ float m[256];
    __shared__ float4 wred[256];
    int t = threadIdx.x;
    int i0 = blockIdx.y * 256;
    {
        float g = 0.f, u = 0.f;
#pragma unroll
        for (int p2 = 0; p2 < 18; ++p2) {
            g += gup[(size_t)p2 * 13824 + i0 + t];
            u += gup[(size_t)p2 * 13824 + FF + i0 + t];
        }
        float gl = 0.5f * g * (1.f + tanhf(0.7978845608028654f * (g + 0.044715f * g * g * g)));
        m[t] = gl * u;
    }
    __syncthreads();
    int f4c = t & 15, ks = t >> 4;           // 16 f4-cols x 16 k-slices (16 rows each)
    int col4 = blockIdx.x * 16 + f4c;        // 0..287
    const float4* W4 = (const float4*)Wd_l;
    int rb = i0 + ks * 16;
    float4 w[16];
#pragma unroll
    for (int r = 0; r < 16; ++r) w[r] = W4[(size_t)(rb + r) * 288 + col4];
    float4 acc = {0, 0, 0, 0};
#pragma unroll
    for (int r = 0; r < 16; ++r) {
        float xs = m[ks * 16 + r];
        acc.x += xs * w[r].x; acc.y += xs * w[r].y;
        acc.z += xs * w[r].z; acc.w += xs * w[r].w;
    }
    wred[t] = acc;
    __syncthreads();
    if (t < 16) {
        float sx = 0, sy = 0, sz = 0, sw = 0;
#pragma unroll
        for (int k2 = 0; k2 < 16; ++k2) {
            float4 r = wred[k2 * 16 + t];
            sx += r.x; sy += r.y; sz += r.z; sw += r.w;
        }
        float* dst = dpp + (size_t)blockIdx.y * DM + 4 * (blockIdx.x * 16 + t);
        dst[0] = sx; dst[1] = sy; dst[2] = sz; dst[3] = sw;
    }
}

// ---------------- logits: redundant prefix + full-K GEMV + fused argmax, grid(512) ----------------
__global__ __launch_bounds__(256) void gk_logits(
    const float* __restrict__ W_lm,
    const float* __restrict__ hm5, const float* __restrict__ dpp,
    const float* __restrict__ wpof5, const float* __restrict__ wfin,
    unsigned long long* __restrict__ amx, unsigned int* __restrict__ cnt,
    float* __restrict__ tok_out) {
    __shared__ float xv[DM];
    __shared__ float red4[4];
    __shared__ float4 lred[256];
    __shared__ unsigned long long smu[32];
    int t = threadIdx.x;
    // prefix: reduce DPP[27] + residual + double RMS (identical in every block)
    for (int i = t; i < DM; i += 256) {
        float d = 0.f;
#pragma unroll
        for (int p2 = 0; p2 < 27; ++p2) d += dpp[p2 * DM + i];
        xv[i] = d;
    }
    float ss = 0.f;
    for (int i = t; i < DM; i += 256) { float d = xv[i]; ss += d * d; }
    ss = block_sum256(ss, red4);
    float inv = 1.f / sqrtf(ss / DM + EPSV);
    for (int i = t; i < DM; i += 256) xv[i] = hm5[i] + wpof5[i] * xv[i] * inv;
    float s2 = 0.f;
    for (int i = t; i < DM; i += 256) { float v = xv[i]; s2 += v * v; }
    s2 = block_sum256(s2, red4);
    float inv2 = 1.f / sqrtf(s2 / DM + EPSV);
    for (int i = t; i < DM; i += 256) xv[i] = wfin[i] * xv[i] * inv2;
    __syncthreads();

    int f4c = t & 31, ks = t >> 5;           // 32 f4-cols x 8 k-slices of 144 rows
    int colf4 = blockIdx.x * 32 + f4c;       // 0..16383
    const float4* W4 = (const float4*)W_lm;
    float4 acc = {0, 0, 0, 0};
#pragma unroll
    for (int bb = 0; bb < 9; ++bb) {
        int i0 = ks * 144 + bb * 16;
        float4 w[16];
#pragma unroll
        for (int r = 0; r < 16; ++r) w[r] = W4[(size_t)(i0 + r) * 16384 + colf4];
#pragma unroll
        for (int r = 0; r < 16; ++r) {
            float xs = xv[i0 + r];
            acc.x += xs * w[r].x; acc.y += xs * w[r].y;
            acc.z += xs * w[r].z; acc.w += xs * w[r].w;
        }
    }
    lred[t] = acc;
    __syncthreads();
    if (t < 32) {
        float sx = 0, sy = 0, sz = 0, sw = 0;
#pragma unroll
        for (int k2 = 0; k2 < 8; ++k2) {
            float4 r = lred[k2 * 32 + t];
            sx += r.x; sy += r.y; sz += r.z; sw += r.w;
        }
        float lv[4] = {sx, sy, sz, sw};
        int c0 = blockIdx.x * 128 + 4 * t;
        unsigned long long best = 0;
#pragma unroll
        for (int q = 0; q < 4; ++q) {
            unsigned bits = __float_as_uint(lv[q]);
            unsigned key = (bits & 0x80000000u) ? ~bits : (bits | 0x80000000u);
            unsigned long long pk = ((unsigned long long)key << 32) | (unsigned)(~(c0 + q));
            if (pk > best) best = pk;
        }
        smu[t] = best;
    }
    __syncthreads();
    for (int off = 16; off; off >>= 1) {
        if (t < off) { if (smu[t + off] > smu[t]) smu[t] = smu[t + off]; }
        __syncthreads();
    }
    if (t == 0) {
        atomicMax(amx, smu[0]);
        __threadfence();
        if (atomicAdd(cnt, 1u) == 511u) {
            unsigned long long fin = atomicMax(amx, 0ull);   // read via atomic (coherent)
            tok_out[0] = (float)(~(unsigned)(fin & 0xFFFFFFFFull));
        }
    }
}

// ==================== host launcher ====================
extern "C" void kernel_launch(void* const* d_in, const int* in_sizes, int n_in,
                              void* d_out, int out_size, void* d_ws, size_t ws_size,
                              hipStream_t stream) {
    const int*   ids   = (const int*)d_in[0];
    const int*   aflag = (const int*)d_in[1];
    const float* kc    = (const float*)d_in[2];
    const float* vc    = (const float*)d_in[3];
    const int*   tbl   = (const int*)d_in[4];
    const float* esc   = (const float*)d_in[5];
    const float* ezp   = (const float*)d_in[6];
    const float* w_in  = (const float*)d_in[7];
    const float* w_qn  = (const float*)d_in[8];
    const float* w_kn  = (const float*)d_in[9];
    const float* Wq    = (const float*)d_in[10];
    const float* Wk    = (const float*)d_in[11];
    const float* Wv    = (const float*)d_in[12];
    const float* Wo    = (const float*)d_in[13];
    const float* w_pa  = (const float*)d_in[14];
    const float* w_pf  = (const float*)d_in[15];
    const float* w_pof = (const float*)d_in[16];
    const float* Wg    = (const float*)d_in[17];
    const float* Wu    = (const float*)d_in[18];
    const float* Wd    = (const float*)d_in[19];
    const float* w_fin = (const float*)d_in[20];
    const float* Wlm   = (const float*)d_in[21];

    float* keys = (float*)d_out;
    float* vals = keys + (size_t)LNUM * DHEAD * SEQ;
    float* tok  = vals + (size_t)LNUM * SEQ * DHEAD;
    float* ws = (float*)d_ws;
    unsigned int* cnts = (unsigned int*)(ws + CNT_O);
    unsigned long long* amx = (unsigned long long*)(ws + AMX_O);

    gk_copy<<<24576 + 6144, 256, 0, stream>>>(
        kc, vc, keys, vals, ids, tbl, esc, ezp,
        w_in, ws + HIN_O, ws + XN0_O, cnts, amx);

    for (int l = 0; l < LNUM; ++l) {
        float* keys_l = keys + (size_t)l * DHEAD * SEQ;
        float* vals_l = vals + (size_t)l * SEQ * DHEAD;

        gk_qkv<<<dim3(6, 18), 256, 0, stream>>>(
            Wq + (size_t)l * DM * 1024, Wk + (size_t)l * DM * 256,
            Wv + (size_t)l * DM * 256,
            w_in + (size_t)l * DM,
            (l ? w_pof + (size_t)(l - 1) * DM : w_in),
            ws + HM_O, ws + DPP_O, ws + XN0_O,
            ws + HIN_O, ws + QKVP_O, (l > 0) ? 1 : 0);

        gk_attn<<<128, 256, 0, stream>>>(
            ws + QKVP_O, w_qn + (size_t)l * DHEAD, w_kn + (size_t)l * DHEAD,
            aflag, keys_l, vals_l, ws + POP_O, ws + SPS_O,
            ((l % 6) != 5) ? 1000000.0f : 10000.0f);

        gk_wo<<<dim3(5, 16), 256, 0, stream>>>(
            ws + POP_O, ws + SPS_O, Wo + (size_t)l * 1024 * DM, ws + APP_O);

        gk_gu<<<dim3(54, 18), 256, 0, stream>>>(
            Wg + (size_t)l * DM * FF, Wu + (size_t)l * DM * FF,
            w_pa + (size_t)l * DM, w_pf + (size_t)l * DM,
            ws + HIN_O, ws + APP_O, ws + HM_O, ws + GUP_O);

        gk_wd<<<dim3(18, 27), 256, 0, stream>>>(
            ws + GUP_O, Wd + (size_t)l * FF * DM, ws + DPP_O);
    }

    gk_logits<<<512, 256, 0, stream>>>(
        Wlm, ws + HM_O, ws + DPP_O,
        w_pof + (size_t)5 * DM, w_fin, amx, &cnts[0], tok);
}